// Round 14
// baseline (189.497 us; speedup 1.0000x reference)
//
#include <hip/hip_runtime.h>
#include <cstddef>
#include <cstdint>

#define THREADS 256
#define KPART 256        // partition blocks
#define MAXNB 1600       // max buckets (N<=51200); N=50000 -> NB=1563

typedef short bf16x8 __attribute__((ext_vector_type(8)));
typedef float f32x4 __attribute__((ext_vector_type(4)));
typedef unsigned short u16x8 __attribute__((ext_vector_type(8)));

#define GLOBAL_AS __attribute__((address_space(1)))
#define LDS_AS    __attribute__((address_space(3)))

__device__ __forceinline__ void async_copy16(const void* g, void* l) {
    __builtin_amdgcn_global_load_lds((const GLOBAL_AS void*)g, (LDS_AS void*)l, 16, 0, 0);
}

__device__ __forceinline__ ushort f2bf(float f) {
    uint32_t u = __float_as_uint(f);
    u = u + 0x7FFFu + ((u >> 16) & 1u);
    return (ushort)(u >> 16);
}
__device__ __forceinline__ float bf2f(ushort h) {
    return __uint_as_float(((uint32_t)h) << 16);
}

// ---------------------------------------------------------------------------
// f32 vector micro-GEMM pieces (used only by wpow)
// ---------------------------------------------------------------------------
__device__ __forceinline__ void rowfma(float4& acc, const float4 xv,
                                       const float4 w0, const float4 w1,
                                       const float4 w2, const float4 w3) {
    acc.x = fmaf(xv.x, w0.x, acc.x); acc.y = fmaf(xv.x, w0.y, acc.y);
    acc.z = fmaf(xv.x, w0.z, acc.z); acc.w = fmaf(xv.x, w0.w, acc.w);
    acc.x = fmaf(xv.y, w1.x, acc.x); acc.y = fmaf(xv.y, w1.y, acc.y);
    acc.z = fmaf(xv.y, w1.z, acc.z); acc.w = fmaf(xv.y, w1.w, acc.w);
    acc.x = fmaf(xv.z, w2.x, acc.x); acc.y = fmaf(xv.z, w2.y, acc.y);
    acc.z = fmaf(xv.z, w2.z, acc.z); acc.w = fmaf(xv.z, w2.w, acc.w);
    acc.x = fmaf(xv.w, w3.x, acc.x); acc.y = fmaf(xv.w, w3.y, acc.y);
    acc.z = fmaf(xv.w, w3.z, acc.z); acc.w = fmaf(xv.w, w3.w, acc.w);
}

__device__ __forceinline__ void mm32(const float4* Ws4, const float4* Xs4,
                                     int c4, int rb,
                                     float4& a0, float4& a1, float4& a2, float4& a3) {
#pragma unroll 4
    for (int kq = 0; kq < 32; ++kq) {
        float4 w0 = Ws4[(4 * kq + 0) * 32 + c4];
        float4 w1 = Ws4[(4 * kq + 1) * 32 + c4];
        float4 w2 = Ws4[(4 * kq + 2) * 32 + c4];
        float4 w3 = Ws4[(4 * kq + 3) * 32 + c4];
        float4 x0 = Xs4[(rb + 0) * 32 + kq];
        float4 x1 = Xs4[(rb + 1) * 32 + kq];
        float4 x2 = Xs4[(rb + 2) * 32 + kq];
        float4 x3 = Xs4[(rb + 3) * 32 + kq];
        rowfma(a0, x0, w0, w1, w2, w3);
        rowfma(a1, x1, w0, w1, w2, w3);
        rowfma(a2, x2, w0, w1, w2, w3);
        rowfma(a3, x3, w0, w1, w2, w3);
    }
}

// ---------------------------------------------------------------------------
// wpow: -W^2 and W^3 -> transposed, hi/lo-split, XOR-swizzled bf16 tables.
// u16 idx = col*128 + (k ^ ((col&7)<<3)).
// ---------------------------------------------------------------------------
__global__ __launch_bounds__(256, 2)
void wpow_kernel(const float* __restrict__ W,
                 ushort* __restrict__ w3t_hi, ushort* __restrict__ w3t_lo,
                 ushort* __restrict__ nw2t_hi, ushort* __restrict__ nw2t_lo) {
    __shared__ float4 Ws4[128 * 32];
    __shared__ float4 Xs4[32 * 32];
    const int tid = threadIdx.x;
    const int row0 = (blockIdx.x & 3) * 32;
    const bool is3 = blockIdx.x >= 4;
    const float4* __restrict__ W4 = (const float4*)W;

#pragma unroll
    for (int i = 0; i < 16; ++i) Ws4[tid + i * 256] = W4[tid + i * 256];
#pragma unroll
    for (int i = 0; i < 4; ++i) {
        int li = tid + i * 256;
        Xs4[li] = W4[(size_t)(row0 + (li >> 5)) * 32 + (li & 31)];
    }
    __syncthreads();

    const int c4 = tid & 31;
    const int rb = (tid >> 5) * 4;
    float4 a0 = {0.f, 0.f, 0.f, 0.f};
    float4 a1 = {0.f, 0.f, 0.f, 0.f};
    float4 a2 = {0.f, 0.f, 0.f, 0.f};
    float4 a3 = {0.f, 0.f, 0.f, 0.f};
    mm32(Ws4, Xs4, c4, rb, a0, a1, a2, a3);

    if (is3) {
        __syncthreads();
        Xs4[(rb + 0) * 32 + c4] = a0;
        Xs4[(rb + 1) * 32 + c4] = a1;
        Xs4[(rb + 2) * 32 + c4] = a2;
        Xs4[(rb + 3) * 32 + c4] = a3;
        __syncthreads();
        a0 = {0.f, 0.f, 0.f, 0.f};
        a1 = {0.f, 0.f, 0.f, 0.f};
        a2 = {0.f, 0.f, 0.f, 0.f};
        a3 = {0.f, 0.f, 0.f, 0.f};
        mm32(Ws4, Xs4, c4, rb, a0, a1, a2, a3);
    }

    ushort* __restrict__ dh = is3 ? w3t_hi : nw2t_hi;
    ushort* __restrict__ dl = is3 ? w3t_lo : nw2t_lo;
    const float sgn = is3 ? 1.0f : -1.0f;
    const int r = row0 + rb;
#pragma unroll
    for (int i = 0; i < 4; ++i) {
        float4 a = (i == 0) ? a0 : (i == 1) ? a1 : (i == 2) ? a2 : a3;
        const int k = r + i;
#pragma unroll
        for (int e = 0; e < 4; ++e) {
            float v = ((e == 0) ? a.x : (e == 1) ? a.y : (e == 2) ? a.z : a.w) * sgn;
            int c = c4 * 4 + e;
            int idx = c * 128 + (k ^ ((c & 7) << 3));
            ushort h = f2bf(v);
            dh[idx] = h;
            dl[idx] = f2bf(v - bf2f(h));
        }
    }
}

// ---------------------------------------------------------------------------
// Dual GEMM via bf16 hi/lo-split MFMA (R6-verified structure).
// ---------------------------------------------------------------------------
__global__ __launch_bounds__(256, 2)
void gemm_dual_mfma(const float* __restrict__ A1, const ushort* __restrict__ B1h,
                    const ushort* __restrict__ B1l,
                    const float* __restrict__ A2, const ushort* __restrict__ B2h,
                    const ushort* __restrict__ B2l,
                    float* __restrict__ out, int N) {
    __shared__ ushort WtHi[16384];
    __shared__ ushort WtLo[16384];
    __shared__ ushort XsHi[4096];
    __shared__ ushort XsLo[4096];
    const int tid = threadIdx.x;
    const int row0 = blockIdx.x * 32;
    const int l = tid & 63, w = tid >> 6;
    const int mt = w & 1, ntb = (w >> 1) * 4;
    const int fr = l & 15, fh = l >> 4;

    f32x4 acc[4];
#pragma unroll
    for (int nt = 0; nt < 4; ++nt) acc[nt] = (f32x4){0.f, 0.f, 0.f, 0.f};

    for (int pass = 0; pass < 2; ++pass) {
        const float* __restrict__ Asrc = pass ? A2 : A1;
        const ushort* __restrict__ Bh = pass ? B2h : B1h;
        const ushort* __restrict__ Bl = pass ? B2l : B1l;
        if (pass) __syncthreads();

#pragma unroll
        for (int i = 0; i < 8; ++i) {
            async_copy16(Bh + tid * 8 + i * 2048, WtHi + tid * 8 + i * 2048);
            async_copy16(Bl + tid * 8 + i * 2048, WtLo + tid * 8 + i * 2048);
        }

        {
            const int row = tid >> 3, kb = (tid & 7) * 16;
            int gr = row0 + row;
            if (gr >= N) gr = N - 1;
            const float4* __restrict__ ap =
                (const float4*)(Asrc + (size_t)gr * 128) + (kb >> 2);
            float4 v0 = ap[0], v1 = ap[1], v2 = ap[2], v3 = ap[3];
            float f[16] = {v0.x, v0.y, v0.z, v0.w, v1.x, v1.y, v1.z, v1.w,
                           v2.x, v2.y, v2.z, v2.w, v3.x, v3.y, v3.z, v3.w};
            ushort hi[16], lo[16];
#pragma unroll
            for (int i = 0; i < 16; ++i) {
                hi[i] = f2bf(f[i]);
                lo[i] = f2bf(f[i] - bf2f(hi[i]));
            }
#pragma unroll
            for (int g = 0; g < 2; ++g) {
                int idx = row * 128 + ((kb + 8 * g) ^ ((row & 7) << 3));
                bf16x8 vh, vl;
#pragma unroll
                for (int j = 0; j < 8; ++j) {
                    vh[j] = (short)hi[8 * g + j];
                    vl[j] = (short)lo[8 * g + j];
                }
                *(bf16x8*)&XsHi[idx] = vh;
                *(bf16x8*)&XsLo[idx] = vl;
            }
        }
        __syncthreads();

#pragma unroll
        for (int ks = 0; ks < 4; ++ks) {
            const int arow = mt * 16 + fr;
            const int aoff = arow * 128 + ((ks * 32 + fh * 8) ^ ((arow & 7) << 3));
            bf16x8 ah = *(const bf16x8*)&XsHi[aoff];
            bf16x8 al = *(const bf16x8*)&XsLo[aoff];
#pragma unroll
            for (int nt = 0; nt < 4; ++nt) {
                const int brow = (ntb + nt) * 16 + fr;
                const int boff = brow * 128 + ((ks * 32 + fh * 8) ^ ((brow & 7) << 3));
                bf16x8 bh = *(const bf16x8*)&WtHi[boff];
                bf16x8 bl = *(const bf16x8*)&WtLo[boff];
                acc[nt] = __builtin_amdgcn_mfma_f32_16x16x32_bf16(ah, bh, acc[nt], 0, 0, 0);
                acc[nt] = __builtin_amdgcn_mfma_f32_16x16x32_bf16(al, bh, acc[nt], 0, 0, 0);
                acc[nt] = __builtin_amdgcn_mfma_f32_16x16x32_bf16(ah, bl, acc[nt], 0, 0, 0);
            }
        }
    }

#pragma unroll
    for (int nt = 0; nt < 4; ++nt) {
        const int col = (ntb + nt) * 16 + fr;
#pragma unroll
        for (int i = 0; i < 4; ++i) {
            const int rr = row0 + mt * 16 + fh * 4 + i;
            if (rr < N) out[(size_t)rr * 128 + col] = acc[nt][i];
        }
    }
}

// ---------------------------------------------------------------------------
// CSR build: LDS-binned two-pass partition (R10-verified). Buckets = 32 rows.
// ---------------------------------------------------------------------------
__global__ void part_count_conv_kernel(const int* __restrict__ erows, int E,
                                       int* __restrict__ blockcounts, int NB, int chunk,
                                       const float* __restrict__ X,
                                       ushort* __restrict__ Xbf, int ngroups, int cb) {
    __shared__ int hist[MAXNB];
    const int b = blockIdx.x;
    const int tid = threadIdx.x;
    if (b < cb) {
        int i = b * 256 + tid;
        if (i < ngroups) {
            const float4* __restrict__ X4 = (const float4*)X;
            float4 v0 = X4[i * 2 + 0];
            float4 v1 = X4[i * 2 + 1];
            u16x8 o;
            o[0] = f2bf(v0.x); o[1] = f2bf(v0.y); o[2] = f2bf(v0.z); o[3] = f2bf(v0.w);
            o[4] = f2bf(v1.x); o[5] = f2bf(v1.y); o[6] = f2bf(v1.z); o[7] = f2bf(v1.w);
            ((u16x8*)Xbf)[i] = o;
        }
        return;
    }
    const int k = b - cb;
    for (int i = tid; i < NB; i += 256) hist[i] = 0;
    __syncthreads();
    const int e0 = k * chunk;
    const int e1 = (e0 + chunk < E) ? e0 + chunk : E;
    for (int i = e0 + tid; i < e1; i += 256)
        atomicAdd(&hist[erows[i] >> 5], 1);
    __syncthreads();
    for (int i = tid; i < NB; i += 256) blockcounts[i * KPART + k] = hist[i];
}

__global__ void part_scan1_kernel(int* __restrict__ blockcounts,
                                  int* __restrict__ btotal, int NB) {
    const int tid = threadIdx.x;
    const int lane = tid & 63;
    const int b = blockIdx.x * 4 + (tid >> 6);
    if (b >= NB) return;
    int* __restrict__ row = blockcounts + (size_t)b * KPART;
    int c0 = row[lane * 4 + 0];
    int c1 = row[lane * 4 + 1];
    int c2 = row[lane * 4 + 2];
    int c3 = row[lane * 4 + 3];
    int lsum = c0 + c1 + c2 + c3;
    int s = lsum;
#pragma unroll
    for (int off = 1; off < 64; off <<= 1) {
        int t = __shfl_up(s, off);
        if (lane >= off) s += t;
    }
    int run = s - lsum;
    row[lane * 4 + 0] = run; run += c0;
    row[lane * 4 + 1] = run; run += c1;
    row[lane * 4 + 2] = run; run += c2;
    row[lane * 4 + 3] = run;
    if (lane == 63) btotal[b] = s;
}

__global__ __launch_bounds__(1024)
void part_scan2_kernel(const int* __restrict__ btotal, int* __restrict__ bbase,
                       int NB, int E, int* __restrict__ rowptr, int N) {
    __shared__ int sums[1024];
    const int tid = threadIdx.x;
    const int items = (NB + 1023) >> 10;
    const int start = tid * items;
    const int end = (start + items < NB) ? start + items : NB;
    int s = 0;
    for (int i = start; i < end; ++i) s += btotal[i];
    sums[tid] = s;
    __syncthreads();
#pragma unroll
    for (int off = 1; off < 1024; off <<= 1) {
        int t = (tid >= off) ? sums[tid - off] : 0;
        __syncthreads();
        sums[tid] += t;
        __syncthreads();
    }
    int run = sums[tid] - s;
    for (int i = start; i < end; ++i) {
        bbase[i] = run;
        run += btotal[i];
    }
    if (tid == 0) { bbase[NB] = E; rowptr[N] = E; }
}

__global__ void part_place_kernel(const int* __restrict__ erows,
                                  const int* __restrict__ ecols,
                                  const float* __restrict__ evals, int E,
                                  const int* __restrict__ blockcounts,
                                  const int* __restrict__ bbase, int NB, int chunk,
                                  int2* __restrict__ bucketed) {
    __shared__ int cur[MAXNB];
    const int k = blockIdx.x;
    const int tid = threadIdx.x;
    for (int i = tid; i < NB; i += 256)
        cur[i] = bbase[i] + blockcounts[(size_t)i * KPART + k];
    __syncthreads();
    const int e0 = k * chunk;
    const int e1 = (e0 + chunk < E) ? e0 + chunk : E;
    for (int i = e0 + tid; i < e1; i += 256) {
        int r = erows[i];
        int pos = atomicAdd(&cur[r >> 5], 1);  // LDS atomic
        int2 p;
        p.x = (int)(((uint32_t)(r & 31) << 16) | (uint32_t)ecols[i]);
        p.y = __float_as_int(2.0f * evals[i]);
        bucketed[pos] = p;
    }
}

// Emits packed CSR: entry = col<<16 | bf16(2*val).  (col < 65536; val rounding
// 2^-9 rel, same scale as the existing t2 bf16 rounding.)
__global__ void part_finish_kernel(const int2* __restrict__ bucketed,
                                   const int* __restrict__ bbase,
                                   int* __restrict__ rowptr,
                                   uint32_t* __restrict__ csr, int N) {
    __shared__ int rcnt[32];
    __shared__ int rpos[32];
    const int b = blockIdx.x;
    const int tid = threadIdx.x;
    const int base = bbase[b];
    const int end = bbase[b + 1];
    const int row0 = b * 32;
    if (tid < 32) rcnt[tid] = 0;
    __syncthreads();
    for (int i = base + tid; i < end; i += 256)
        atomicAdd(&rcnt[((uint32_t)bucketed[i].x) >> 16], 1);
    __syncthreads();
    if (tid == 0) {
        int run = base;
        for (int j = 0; j < 32; ++j) {
            int c = rcnt[j];
            rpos[j] = run;
            if (row0 + j < N) rowptr[row0 + j] = run;
            run += c;
        }
    }
    __syncthreads();
    for (int i = base + tid; i < end; i += 256) {
        int2 e = bucketed[i];
        uint32_t meta = (uint32_t)e.x;
        int pos = atomicAdd(&rpos[meta >> 16], 1);  // LDS atomic
        csr[pos] = ((meta & 0xFFFFu) << 16) | (uint32_t)f2bf(__int_as_float(e.y));
    }
}

// ---------------------------------------------------------------------------
// XCD-sliced gather SpMM. Feature dim split into 4 slices of 32 feats (64B =
// one cache line). slice = blockIdx%4 -> lands on XCDs {s, s+4} (round-robin
// blockIdx->XCD): per-XCD gather working set = 3.2MB <= 4MB L2, lines reused
// ~16x. CSR (4B/edge) streamed with nontemporal loads so it can't evict the
// slice lines. 8 lanes/row x ushort4; 8-edge unroll, dual accumulators.
// ---------------------------------------------------------------------------
__device__ __forceinline__ void fma4bf(float4& a, float v, ushort4 x) {
    a.x = fmaf(v, bf2f(x.x), a.x);
    a.y = fmaf(v, bf2f(x.y), a.y);
    a.z = fmaf(v, bf2f(x.z), a.z);
    a.w = fmaf(v, bf2f(x.w), a.w);
}

template <bool WRITE_BF, bool INIT_SUB>
__global__ __launch_bounds__(256, 8)
void spmm_slice(const int* __restrict__ rowptr, const uint32_t* __restrict__ csr,
                const ushort* __restrict__ src, void* __restrict__ dst, int N) {
    const int s = blockIdx.x & 3;              // feature slice
    const int g = blockIdx.x >> 2;             // row group (32 rows)
    const int fl = threadIdx.x & 7;
    const int row = g * 32 + (threadIdx.x >> 3);
    if (row >= N) return;
    const int base = s * 8 + fl;               // ushort4 index within row (32/row)
    const ushort4* __restrict__ S4 = (const ushort4*)src;

    float4 a0 = {0.f, 0.f, 0.f, 0.f};
    float4 a1 = {0.f, 0.f, 0.f, 0.f};
    if (INIT_SUB) {  // subtract src[row] (bf16 init; error << existing rounding)
        ushort4 t = S4[(size_t)row * 32 + base];
        a0.x = -bf2f(t.x); a0.y = -bf2f(t.y); a0.z = -bf2f(t.z); a0.w = -bf2f(t.w);
    }

    int p = rowptr[row];
    const int p1 = rowptr[row + 1];
    for (; p + 7 < p1; p += 8) {
        uint32_t e0 = __builtin_nontemporal_load(csr + p + 0);
        uint32_t e1 = __builtin_nontemporal_load(csr + p + 1);
        uint32_t e2 = __builtin_nontemporal_load(csr + p + 2);
        uint32_t e3 = __builtin_nontemporal_load(csr + p + 3);
        uint32_t e4 = __builtin_nontemporal_load(csr + p + 4);
        uint32_t e5 = __builtin_nontemporal_load(csr + p + 5);
        uint32_t e6 = __builtin_nontemporal_load(csr + p + 6);
        uint32_t e7 = __builtin_nontemporal_load(csr + p + 7);
        ushort4 x0 = S4[(size_t)(e0 >> 16) * 32 + base];
        ushort4 x1 = S4[(size_t)(e1 >> 16) * 32 + base];
        ushort4 x2 = S4[(size_t)(e2 >> 16) * 32 + base];
        ushort4 x3 = S4[(size_t)(e3 >> 16) * 32 + base];
        ushort4 x4 = S4[(size_t)(e4 >> 16) * 32 + base];
        ushort4 x5 = S4[(size_t)(e5 >> 16) * 32 + base];
        ushort4 x6 = S4[(size_t)(e6 >> 16) * 32 + base];
        ushort4 x7 = S4[(size_t)(e7 >> 16) * 32 + base];
        fma4bf(a0, bf2f((ushort)(e0 & 0xFFFFu)), x0);
        fma4bf(a1, bf2f((ushort)(e1 & 0xFFFFu)), x1);
        fma4bf(a0, bf2f((ushort)(e2 & 0xFFFFu)), x2);
        fma4bf(a1, bf2f((ushort)(e3 & 0xFFFFu)), x3);
        fma4bf(a0, bf2f((ushort)(e4 & 0xFFFFu)), x4);
        fma4bf(a1, bf2f((ushort)(e5 & 0xFFFFu)), x5);
        fma4bf(a0, bf2f((ushort)(e6 & 0xFFFFu)), x6);
        fma4bf(a1, bf2f((ushort)(e7 & 0xFFFFu)), x7);
    }
    for (; p + 3 < p1; p += 4) {
        uint32_t e0 = __builtin_nontemporal_load(csr + p + 0);
        uint32_t e1 = __builtin_nontemporal_load(csr + p + 1);
        uint32_t e2 = __builtin_nontemporal_load(csr + p + 2);
        uint32_t e3 = __builtin_nontemporal_load(csr + p + 3);
        ushort4 x0 = S4[(size_t)(e0 >> 16) * 32 + base];
        ushort4 x1 = S4[(size_t)(e1 >> 16) * 32 + base];
        ushort4 x2 = S4[(size_t)(e2 >> 16) * 32 + base];
        ushort4 x3 = S4[(size_t)(e3 >> 16) * 32 + base];
        fma4bf(a0, bf2f((ushort)(e0 & 0xFFFFu)), x0);
        fma4bf(a1, bf2f((ushort)(e1 & 0xFFFFu)), x1);
        fma4bf(a0, bf2f((ushort)(e2 & 0xFFFFu)), x2);
        fma4bf(a1, bf2f((ushort)(e3 & 0xFFFFu)), x3);
    }
    for (; p < p1; ++p) {
        uint32_t e = __builtin_nontemporal_load(csr + p);
        ushort4 x = S4[(size_t)(e >> 16) * 32 + base];
        fma4bf(a0, bf2f((ushort)(e & 0xFFFFu)), x);
    }
    float4 acc;
    acc.x = a0.x + a1.x;
    acc.y = a0.y + a1.y;
    acc.z = a0.z + a1.z;
    acc.w = a0.w + a1.w;
    if (WRITE_BF) {
        ushort4 o;
        o.x = f2bf(acc.x); o.y = f2bf(acc.y); o.z = f2bf(acc.z); o.w = f2bf(acc.w);
        ((ushort4*)dst)[(size_t)row * 32 + base] = o;
    } else {
        f32x4 v = {acc.x, acc.y, acc.z, acc.w};
        __builtin_nontemporal_store(v, (f32x4*)dst + (size_t)row * 32 + base);
    }
}

extern "C" void kernel_launch(void* const* d_in, const int* in_sizes, int n_in,
                              void* d_out, int out_size, void* d_ws, size_t ws_size,
                              hipStream_t stream) {
    const float* X     = (const float*)d_in[0];
    const int*   erows = (const int*)d_in[1];
    const int*   ecols = (const int*)d_in[2];
    const float* evals = (const float*)d_in[3];
    const float* W     = (const float*)d_in[4];
    float* out = (float*)d_out;

    const int N = in_sizes[0] / 128;  // 50000 (cols fit 16 bits; NB <= MAXNB)
    const int E = in_sizes[1];        // 800000

    // Workspace layout (bases 16B-aligned). bucketed aliases u2: the
    // intermediate dies in part_finish, before spmm2 writes u2.
    ushort*   t2bf    = (ushort*)d_ws;                    // N*128 u16
    float*    u2      = (float*)(t2bf + (size_t)N * 128); // N*128 f32
    int2*     bucketed= (int2*)u2;                        // E int2 (alias)
    ushort*   xbf     = (ushort*)(u2 + (size_t)N * 128);  // N*128 u16
    ushort*   wtab    = xbf + (size_t)N * 128;            // 65536 u16
    ushort*   w3t_hi  = wtab;
    ushort*   w3t_lo  = wtab + 16384;
    ushort*   nw2t_hi = wtab + 32768;
    ushort*   nw2t_lo = wtab + 49152;
    uint32_t* csr     = (uint32_t*)(wtab + 65536);        // E u32 (packed)
    int*      rowptr  = (int*)(csr + E);                  // N+1
    int*      blkcnt  = rowptr + (N + 1);                 // NB*KPART
    const int NB      = (N + 31) >> 5;                    // 1563
    int*      btotal  = blkcnt + (size_t)NB * KPART;      // NB
    int*      bbase   = btotal + NB;                      // NB+1

    const int chunk    = (E + KPART - 1) / KPART;         // 3125
    const int ngroups  = N * 16;
    const int cb       = (ngroups + 255) / 256;
    const int d_blocks = (N + 31) / 32;
    const int sl_blocks = ((N + 31) / 32) * 4;            // (row-group, slice)

    // --- W powers ---
    wpow_kernel<<<8, THREADS, 0, stream>>>(W, w3t_hi, w3t_lo, nw2t_hi, nw2t_lo);

    // --- CSR build: LDS-binned two-pass partition (+ fused X->bf16) ---
    part_count_conv_kernel<<<cb + KPART, THREADS, 0, stream>>>(erows, E, blkcnt, NB,
                                                               chunk, X, xbf, ngroups, cb);
    part_scan1_kernel<<<(NB + 3) / 4, THREADS, 0, stream>>>(blkcnt, btotal, NB);
    part_scan2_kernel<<<1, 1024, 0, stream>>>(btotal, bbase, NB, E, rowptr, N);
    part_place_kernel<<<KPART, THREADS, 0, stream>>>(erows, ecols, evals, E, blkcnt,
                                                     bbase, NB, chunk, bucketed);
    part_finish_kernel<<<NB, THREADS, 0, stream>>>(bucketed, bbase, rowptr, csr, N);

    // --- Chebyshev chain (reassociated) ---
    // t2bf = bf16(2A.Xbf - Xbf)
    spmm_slice<true, true><<<sl_blocks, THREADS, 0, stream>>>(rowptr, csr, xbf, t2bf, N);
    // u2 = 2A.t2bf  (f32; overwrites the dead bucketed alias)
    spmm_slice<false, false><<<sl_blocks, THREADS, 0, stream>>>(rowptr, csr, t2bf, u2, N);
    // out = u2@W3 - X@W2
    gemm_dual_mfma<<<d_blocks, THREADS, 0, stream>>>(u2, w3t_hi, w3t_lo,
                                                     X, nw2t_hi, nw2t_lo, out, N);
}

// Round 15
// 145.932 us; speedup vs baseline: 1.2985x; 1.2985x over previous
//
#include <hip/hip_runtime.h>
#include <cstddef>
#include <cstdint>

#define THREADS 256
#define KPART 256        // partition blocks
#define MAXNB 1600       // max buckets (N<=51200); N=50000 -> NB=1563

typedef short bf16x8 __attribute__((ext_vector_type(8)));
typedef float f32x4 __attribute__((ext_vector_type(4)));
typedef unsigned short u16x8 __attribute__((ext_vector_type(8)));

#define GLOBAL_AS __attribute__((address_space(1)))
#define LDS_AS    __attribute__((address_space(3)))

__device__ __forceinline__ void async_copy16(const void* g, void* l) {
    __builtin_amdgcn_global_load_lds((const GLOBAL_AS void*)g, (LDS_AS void*)l, 16, 0, 0);
}

__device__ __forceinline__ ushort f2bf(float f) {
    uint32_t u = __float_as_uint(f);
    u = u + 0x7FFFu + ((u >> 16) & 1u);
    return (ushort)(u >> 16);
}
__device__ __forceinline__ float bf2f(ushort h) {
    return __uint_as_float(((uint32_t)h) << 16);
}

// ---------------------------------------------------------------------------
// f32 vector micro-GEMM pieces (used only by wpow)
// ---------------------------------------------------------------------------
__device__ __forceinline__ void rowfma(float4& acc, const float4 xv,
                                       const float4 w0, const float4 w1,
                                       const float4 w2, const float4 w3) {
    acc.x = fmaf(xv.x, w0.x, acc.x); acc.y = fmaf(xv.x, w0.y, acc.y);
    acc.z = fmaf(xv.x, w0.z, acc.z); acc.w = fmaf(xv.x, w0.w, acc.w);
    acc.x = fmaf(xv.y, w1.x, acc.x); acc.y = fmaf(xv.y, w1.y, acc.y);
    acc.z = fmaf(xv.y, w1.z, acc.z); acc.w = fmaf(xv.y, w1.w, acc.w);
    acc.x = fmaf(xv.z, w2.x, acc.x); acc.y = fmaf(xv.z, w2.y, acc.y);
    acc.z = fmaf(xv.z, w2.z, acc.z); acc.w = fmaf(xv.z, w2.w, acc.w);
    acc.x = fmaf(xv.w, w3.x, acc.x); acc.y = fmaf(xv.w, w3.y, acc.y);
    acc.z = fmaf(xv.w, w3.z, acc.z); acc.w = fmaf(xv.w, w3.w, acc.w);
}

__device__ __forceinline__ void mm32(const float4* Ws4, const float4* Xs4,
                                     int c4, int rb,
                                     float4& a0, float4& a1, float4& a2, float4& a3) {
#pragma unroll 4
    for (int kq = 0; kq < 32; ++kq) {
        float4 w0 = Ws4[(4 * kq + 0) * 32 + c4];
        float4 w1 = Ws4[(4 * kq + 1) * 32 + c4];
        float4 w2 = Ws4[(4 * kq + 2) * 32 + c4];
        float4 w3 = Ws4[(4 * kq + 3) * 32 + c4];
        float4 x0 = Xs4[(rb + 0) * 32 + kq];
        float4 x1 = Xs4[(rb + 1) * 32 + kq];
        float4 x2 = Xs4[(rb + 2) * 32 + kq];
        float4 x3 = Xs4[(rb + 3) * 32 + kq];
        rowfma(a0, x0, w0, w1, w2, w3);
        rowfma(a1, x1, w0, w1, w2, w3);
        rowfma(a2, x2, w0, w1, w2, w3);
        rowfma(a3, x3, w0, w1, w2, w3);
    }
}

// ---------------------------------------------------------------------------
// wpow: -W^2 and W^3 -> transposed, hi/lo-split, XOR-swizzled bf16 tables.
// u16 idx = col*128 + (k ^ ((col&7)<<3)).
// ---------------------------------------------------------------------------
__global__ __launch_bounds__(256, 2)
void wpow_kernel(const float* __restrict__ W,
                 ushort* __restrict__ w3t_hi, ushort* __restrict__ w3t_lo,
                 ushort* __restrict__ nw2t_hi, ushort* __restrict__ nw2t_lo) {
    __shared__ float4 Ws4[128 * 32];
    __shared__ float4 Xs4[32 * 32];
    const int tid = threadIdx.x;
    const int row0 = (blockIdx.x & 3) * 32;
    const bool is3 = blockIdx.x >= 4;
    const float4* __restrict__ W4 = (const float4*)W;

#pragma unroll
    for (int i = 0; i < 16; ++i) Ws4[tid + i * 256] = W4[tid + i * 256];
#pragma unroll
    for (int i = 0; i < 4; ++i) {
        int li = tid + i * 256;
        Xs4[li] = W4[(size_t)(row0 + (li >> 5)) * 32 + (li & 31)];
    }
    __syncthreads();

    const int c4 = tid & 31;
    const int rb = (tid >> 5) * 4;
    float4 a0 = {0.f, 0.f, 0.f, 0.f};
    float4 a1 = {0.f, 0.f, 0.f, 0.f};
    float4 a2 = {0.f, 0.f, 0.f, 0.f};
    float4 a3 = {0.f, 0.f, 0.f, 0.f};
    mm32(Ws4, Xs4, c4, rb, a0, a1, a2, a3);

    if (is3) {
        __syncthreads();
        Xs4[(rb + 0) * 32 + c4] = a0;
        Xs4[(rb + 1) * 32 + c4] = a1;
        Xs4[(rb + 2) * 32 + c4] = a2;
        Xs4[(rb + 3) * 32 + c4] = a3;
        __syncthreads();
        a0 = {0.f, 0.f, 0.f, 0.f};
        a1 = {0.f, 0.f, 0.f, 0.f};
        a2 = {0.f, 0.f, 0.f, 0.f};
        a3 = {0.f, 0.f, 0.f, 0.f};
        mm32(Ws4, Xs4, c4, rb, a0, a1, a2, a3);
    }

    ushort* __restrict__ dh = is3 ? w3t_hi : nw2t_hi;
    ushort* __restrict__ dl = is3 ? w3t_lo : nw2t_lo;
    const float sgn = is3 ? 1.0f : -1.0f;
    const int r = row0 + rb;
#pragma unroll
    for (int i = 0; i < 4; ++i) {
        float4 a = (i == 0) ? a0 : (i == 1) ? a1 : (i == 2) ? a2 : a3;
        const int k = r + i;
#pragma unroll
        for (int e = 0; e < 4; ++e) {
            float v = ((e == 0) ? a.x : (e == 1) ? a.y : (e == 2) ? a.z : a.w) * sgn;
            int c = c4 * 4 + e;
            int idx = c * 128 + (k ^ ((c & 7) << 3));
            ushort h = f2bf(v);
            dh[idx] = h;
            dl[idx] = f2bf(v - bf2f(h));
        }
    }
}

// ---------------------------------------------------------------------------
// Dual GEMM via bf16 hi/lo-split MFMA (R6-verified structure).
// ---------------------------------------------------------------------------
__global__ __launch_bounds__(256, 2)
void gemm_dual_mfma(const float* __restrict__ A1, const ushort* __restrict__ B1h,
                    const ushort* __restrict__ B1l,
                    const float* __restrict__ A2, const ushort* __restrict__ B2h,
                    const ushort* __restrict__ B2l,
                    float* __restrict__ out, int N) {
    __shared__ ushort WtHi[16384];
    __shared__ ushort WtLo[16384];
    __shared__ ushort XsHi[4096];
    __shared__ ushort XsLo[4096];
    const int tid = threadIdx.x;
    const int row0 = blockIdx.x * 32;
    const int l = tid & 63, w = tid >> 6;
    const int mt = w & 1, ntb = (w >> 1) * 4;
    const int fr = l & 15, fh = l >> 4;

    f32x4 acc[4];
#pragma unroll
    for (int nt = 0; nt < 4; ++nt) acc[nt] = (f32x4){0.f, 0.f, 0.f, 0.f};

    for (int pass = 0; pass < 2; ++pass) {
        const float* __restrict__ Asrc = pass ? A2 : A1;
        const ushort* __restrict__ Bh = pass ? B2h : B1h;
        const ushort* __restrict__ Bl = pass ? B2l : B1l;
        if (pass) __syncthreads();

#pragma unroll
        for (int i = 0; i < 8; ++i) {
            async_copy16(Bh + tid * 8 + i * 2048, WtHi + tid * 8 + i * 2048);
            async_copy16(Bl + tid * 8 + i * 2048, WtLo + tid * 8 + i * 2048);
        }

        {
            const int row = tid >> 3, kb = (tid & 7) * 16;
            int gr = row0 + row;
            if (gr >= N) gr = N - 1;
            const float4* __restrict__ ap =
                (const float4*)(Asrc + (size_t)gr * 128) + (kb >> 2);
            float4 v0 = ap[0], v1 = ap[1], v2 = ap[2], v3 = ap[3];
            float f[16] = {v0.x, v0.y, v0.z, v0.w, v1.x, v1.y, v1.z, v1.w,
                           v2.x, v2.y, v2.z, v2.w, v3.x, v3.y, v3.z, v3.w};
            ushort hi[16], lo[16];
#pragma unroll
            for (int i = 0; i < 16; ++i) {
                hi[i] = f2bf(f[i]);
                lo[i] = f2bf(f[i] - bf2f(hi[i]));
            }
#pragma unroll
            for (int g = 0; g < 2; ++g) {
                int idx = row * 128 + ((kb + 8 * g) ^ ((row & 7) << 3));
                bf16x8 vh, vl;
#pragma unroll
                for (int j = 0; j < 8; ++j) {
                    vh[j] = (short)hi[8 * g + j];
                    vl[j] = (short)lo[8 * g + j];
                }
                *(bf16x8*)&XsHi[idx] = vh;
                *(bf16x8*)&XsLo[idx] = vl;
            }
        }
        __syncthreads();

#pragma unroll
        for (int ks = 0; ks < 4; ++ks) {
            const int arow = mt * 16 + fr;
            const int aoff = arow * 128 + ((ks * 32 + fh * 8) ^ ((arow & 7) << 3));
            bf16x8 ah = *(const bf16x8*)&XsHi[aoff];
            bf16x8 al = *(const bf16x8*)&XsLo[aoff];
#pragma unroll
            for (int nt = 0; nt < 4; ++nt) {
                const int brow = (ntb + nt) * 16 + fr;
                const int boff = brow * 128 + ((ks * 32 + fh * 8) ^ ((brow & 7) << 3));
                bf16x8 bh = *(const bf16x8*)&WtHi[boff];
                bf16x8 bl = *(const bf16x8*)&WtLo[boff];
                acc[nt] = __builtin_amdgcn_mfma_f32_16x16x32_bf16(ah, bh, acc[nt], 0, 0, 0);
                acc[nt] = __builtin_amdgcn_mfma_f32_16x16x32_bf16(al, bh, acc[nt], 0, 0, 0);
                acc[nt] = __builtin_amdgcn_mfma_f32_16x16x32_bf16(ah, bl, acc[nt], 0, 0, 0);
            }
        }
    }

#pragma unroll
    for (int nt = 0; nt < 4; ++nt) {
        const int col = (ntb + nt) * 16 + fr;
#pragma unroll
        for (int i = 0; i < 4; ++i) {
            const int rr = row0 + mt * 16 + fh * 4 + i;
            if (rr < N) out[(size_t)rr * 128 + col] = acc[nt][i];
        }
    }
}

// ---------------------------------------------------------------------------
// CSR build: LDS-binned two-pass partition (R10-verified). Buckets = 32 rows.
// ---------------------------------------------------------------------------
__global__ void part_count_conv_kernel(const int* __restrict__ erows, int E,
                                       int* __restrict__ blockcounts, int NB, int chunk,
                                       const float* __restrict__ X,
                                       ushort* __restrict__ Xbf, int ngroups, int cb) {
    __shared__ int hist[MAXNB];
    const int b = blockIdx.x;
    const int tid = threadIdx.x;
    if (b < cb) {
        int i = b * 256 + tid;
        if (i < ngroups) {
            const float4* __restrict__ X4 = (const float4*)X;
            float4 v0 = X4[i * 2 + 0];
            float4 v1 = X4[i * 2 + 1];
            u16x8 o;
            o[0] = f2bf(v0.x); o[1] = f2bf(v0.y); o[2] = f2bf(v0.z); o[3] = f2bf(v0.w);
            o[4] = f2bf(v1.x); o[5] = f2bf(v1.y); o[6] = f2bf(v1.z); o[7] = f2bf(v1.w);
            ((u16x8*)Xbf)[i] = o;
        }
        return;
    }
    const int k = b - cb;
    for (int i = tid; i < NB; i += 256) hist[i] = 0;
    __syncthreads();
    const int e0 = k * chunk;
    const int e1 = (e0 + chunk < E) ? e0 + chunk : E;
    for (int i = e0 + tid; i < e1; i += 256)
        atomicAdd(&hist[erows[i] >> 5], 1);
    __syncthreads();
    for (int i = tid; i < NB; i += 256) blockcounts[i * KPART + k] = hist[i];
}

__global__ void part_scan1_kernel(int* __restrict__ blockcounts,
                                  int* __restrict__ btotal, int NB) {
    const int tid = threadIdx.x;
    const int lane = tid & 63;
    const int b = blockIdx.x * 4 + (tid >> 6);
    if (b >= NB) return;
    int* __restrict__ row = blockcounts + (size_t)b * KPART;
    int c0 = row[lane * 4 + 0];
    int c1 = row[lane * 4 + 1];
    int c2 = row[lane * 4 + 2];
    int c3 = row[lane * 4 + 3];
    int lsum = c0 + c1 + c2 + c3;
    int s = lsum;
#pragma unroll
    for (int off = 1; off < 64; off <<= 1) {
        int t = __shfl_up(s, off);
        if (lane >= off) s += t;
    }
    int run = s - lsum;
    row[lane * 4 + 0] = run; run += c0;
    row[lane * 4 + 1] = run; run += c1;
    row[lane * 4 + 2] = run; run += c2;
    row[lane * 4 + 3] = run;
    if (lane == 63) btotal[b] = s;
}

__global__ __launch_bounds__(1024)
void part_scan2_kernel(const int* __restrict__ btotal, int* __restrict__ bbase,
                       int NB, int E, int* __restrict__ rowptr, int N) {
    __shared__ int sums[1024];
    const int tid = threadIdx.x;
    const int items = (NB + 1023) >> 10;
    const int start = tid * items;
    const int end = (start + items < NB) ? start + items : NB;
    int s = 0;
    for (int i = start; i < end; ++i) s += btotal[i];
    sums[tid] = s;
    __syncthreads();
#pragma unroll
    for (int off = 1; off < 1024; off <<= 1) {
        int t = (tid >= off) ? sums[tid - off] : 0;
        __syncthreads();
        sums[tid] += t;
        __syncthreads();
    }
    int run = sums[tid] - s;
    for (int i = start; i < end; ++i) {
        bbase[i] = run;
        run += btotal[i];
    }
    if (tid == 0) { bbase[NB] = E; rowptr[N] = E; }
}

__global__ void part_place_kernel(const int* __restrict__ erows,
                                  const int* __restrict__ ecols,
                                  const float* __restrict__ evals, int E,
                                  const int* __restrict__ blockcounts,
                                  const int* __restrict__ bbase, int NB, int chunk,
                                  int2* __restrict__ bucketed) {
    __shared__ int cur[MAXNB];
    const int k = blockIdx.x;
    const int tid = threadIdx.x;
    for (int i = tid; i < NB; i += 256)
        cur[i] = bbase[i] + blockcounts[(size_t)i * KPART + k];
    __syncthreads();
    const int e0 = k * chunk;
    const int e1 = (e0 + chunk < E) ? e0 + chunk : E;
    for (int i = e0 + tid; i < e1; i += 256) {
        int r = erows[i];
        int pos = atomicAdd(&cur[r >> 5], 1);  // LDS atomic
        int2 p;
        p.x = (int)(((uint32_t)(r & 31) << 16) | (uint32_t)ecols[i]);
        p.y = __float_as_int(2.0f * evals[i]);
        bucketed[pos] = p;
    }
}

// Emits packed CSR: entry = col<<16 | bf16(2*val).  (col < 65536; val rounding
// 2^-9 rel — proven in R14's passing run, absmax unchanged at 0.03125.)
__global__ void part_finish_kernel(const int2* __restrict__ bucketed,
                                   const int* __restrict__ bbase,
                                   int* __restrict__ rowptr,
                                   uint32_t* __restrict__ csr, int N) {
    __shared__ int rcnt[32];
    __shared__ int rpos[32];
    const int b = blockIdx.x;
    const int tid = threadIdx.x;
    const int base = bbase[b];
    const int end = bbase[b + 1];
    const int row0 = b * 32;
    if (tid < 32) rcnt[tid] = 0;
    __syncthreads();
    for (int i = base + tid; i < end; i += 256)
        atomicAdd(&rcnt[((uint32_t)bucketed[i].x) >> 16], 1);
    __syncthreads();
    if (tid == 0) {
        int run = base;
        for (int j = 0; j < 32; ++j) {
            int c = rcnt[j];
            rpos[j] = run;
            if (row0 + j < N) rowptr[row0 + j] = run;
            run += c;
        }
    }
    __syncthreads();
    for (int i = base + tid; i < end; i += 256) {
        int2 e = bucketed[i];
        uint32_t meta = (uint32_t)e.x;
        int pos = atomicAdd(&rpos[meta >> 16], 1);  // LDS atomic
        csr[pos] = ((meta & 0xFFFFu) << 16) | (uint32_t)f2bf(__int_as_float(e.y));
    }
}

// ---------------------------------------------------------------------------
// Gather SpMM over bf16 source (R10-verified 32-lane structure; packed 4B CSR).
// S[row] = sum_e 2*val_e * src[col_e] (- init[row] if init).
// 32 lanes/row, ushort4 per lane, 8-edge unrolled, dual accumulators.
// ---------------------------------------------------------------------------
__device__ __forceinline__ void fma4bf(float4& a, float v, ushort4 x) {
    a.x = fmaf(v, bf2f(x.x), a.x);
    a.y = fmaf(v, bf2f(x.y), a.y);
    a.z = fmaf(v, bf2f(x.z), a.z);
    a.w = fmaf(v, bf2f(x.w), a.w);
}

template <bool WRITE_BF>
__global__ __launch_bounds__(256, 8)
void spmm_gather_bf(const int* __restrict__ rowptr, const uint32_t* __restrict__ csr,
                    const ushort* __restrict__ src, const float* __restrict__ init,
                    void* __restrict__ dst, int N) {
    long long idx = (long long)blockIdx.x * blockDim.x + threadIdx.x;
    int row = (int)(idx >> 5);
    if (row >= N) return;
    int lane = (int)(idx & 31);
    const ushort4* __restrict__ S4 = (const ushort4*)src;  // [col*32 + lane]
    float4 accA = {0.f, 0.f, 0.f, 0.f};
    float4 accB = {0.f, 0.f, 0.f, 0.f};
    if (init) {
        float4 t = ((const float4*)init)[(size_t)row * 32 + lane];
        accA.x = -t.x; accA.y = -t.y; accA.z = -t.z; accA.w = -t.w;
    }
    int p = rowptr[row];
    const int p1 = rowptr[row + 1];
    for (; p + 7 < p1; p += 8) {
        uint32_t e0 = csr[p + 0];
        uint32_t e1 = csr[p + 1];
        uint32_t e2 = csr[p + 2];
        uint32_t e3 = csr[p + 3];
        uint32_t e4 = csr[p + 4];
        uint32_t e5 = csr[p + 5];
        uint32_t e6 = csr[p + 6];
        uint32_t e7 = csr[p + 7];
        ushort4 x0 = S4[(size_t)(e0 >> 16) * 32 + lane];
        ushort4 x1 = S4[(size_t)(e1 >> 16) * 32 + lane];
        ushort4 x2 = S4[(size_t)(e2 >> 16) * 32 + lane];
        ushort4 x3 = S4[(size_t)(e3 >> 16) * 32 + lane];
        ushort4 x4 = S4[(size_t)(e4 >> 16) * 32 + lane];
        ushort4 x5 = S4[(size_t)(e5 >> 16) * 32 + lane];
        ushort4 x6 = S4[(size_t)(e6 >> 16) * 32 + lane];
        ushort4 x7 = S4[(size_t)(e7 >> 16) * 32 + lane];
        fma4bf(accA, bf2f((ushort)(e0 & 0xFFFFu)), x0);
        fma4bf(accB, bf2f((ushort)(e1 & 0xFFFFu)), x1);
        fma4bf(accA, bf2f((ushort)(e2 & 0xFFFFu)), x2);
        fma4bf(accB, bf2f((ushort)(e3 & 0xFFFFu)), x3);
        fma4bf(accA, bf2f((ushort)(e4 & 0xFFFFu)), x4);
        fma4bf(accB, bf2f((ushort)(e5 & 0xFFFFu)), x5);
        fma4bf(accA, bf2f((ushort)(e6 & 0xFFFFu)), x6);
        fma4bf(accB, bf2f((ushort)(e7 & 0xFFFFu)), x7);
    }
    for (; p + 3 < p1; p += 4) {
        uint32_t e0 = csr[p + 0];
        uint32_t e1 = csr[p + 1];
        uint32_t e2 = csr[p + 2];
        uint32_t e3 = csr[p + 3];
        ushort4 x0 = S4[(size_t)(e0 >> 16) * 32 + lane];
        ushort4 x1 = S4[(size_t)(e1 >> 16) * 32 + lane];
        ushort4 x2 = S4[(size_t)(e2 >> 16) * 32 + lane];
        ushort4 x3 = S4[(size_t)(e3 >> 16) * 32 + lane];
        fma4bf(accA, bf2f((ushort)(e0 & 0xFFFFu)), x0);
        fma4bf(accB, bf2f((ushort)(e1 & 0xFFFFu)), x1);
        fma4bf(accA, bf2f((ushort)(e2 & 0xFFFFu)), x2);
        fma4bf(accB, bf2f((ushort)(e3 & 0xFFFFu)), x3);
    }
    for (; p < p1; ++p) {
        uint32_t e = csr[p];
        ushort4 x = S4[(size_t)(e >> 16) * 32 + lane];
        fma4bf(accA, bf2f((ushort)(e & 0xFFFFu)), x);
    }
    float4 acc;
    acc.x = accA.x + accB.x;
    acc.y = accA.y + accB.y;
    acc.z = accA.z + accB.z;
    acc.w = accA.w + accB.w;
    if (WRITE_BF) {
        ushort4 o;
        o.x = f2bf(acc.x); o.y = f2bf(acc.y); o.z = f2bf(acc.z); o.w = f2bf(acc.w);
        ((ushort4*)dst)[(size_t)row * 32 + lane] = o;
    } else {
        ((float4*)dst)[(size_t)row * 32 + lane] = acc;
    }
}

extern "C" void kernel_launch(void* const* d_in, const int* in_sizes, int n_in,
                              void* d_out, int out_size, void* d_ws, size_t ws_size,
                              hipStream_t stream) {
    const float* X     = (const float*)d_in[0];
    const int*   erows = (const int*)d_in[1];
    const int*   ecols = (const int*)d_in[2];
    const float* evals = (const float*)d_in[3];
    const float* W     = (const float*)d_in[4];
    float* out = (float*)d_out;

    const int N = in_sizes[0] / 128;  // 50000 (cols fit 16 bits; NB <= MAXNB)
    const int E = in_sizes[1];        // 800000

    // Workspace layout (bases 16B-aligned). bucketed aliases u2: the
    // intermediate dies in part_finish, before spmm2 writes u2.
    ushort*   t2bf    = (ushort*)d_ws;                    // N*128 u16
    float*    u2      = (float*)(t2bf + (size_t)N * 128); // N*128 f32
    int2*     bucketed= (int2*)u2;                        // E int2 (alias)
    ushort*   xbf     = (ushort*)(u2 + (size_t)N * 128);  // N*128 u16
    ushort*   wtab    = xbf + (size_t)N * 128;            // 65536 u16
    ushort*   w3t_hi  = wtab;
    ushort*   w3t_lo  = wtab + 16384;
    ushort*   nw2t_hi = wtab + 32768;
    ushort*   nw2t_lo = wtab + 49152;
    uint32_t* csr     = (uint32_t*)(wtab + 65536);        // E u32 (packed)
    int*      rowptr  = (int*)(csr + E);                  // N+1
    int*      blkcnt  = rowptr + (N + 1);                 // NB*KPART
    const int NB      = (N + 31) >> 5;                    // 1563
    int*      btotal  = blkcnt + (size_t)NB * KPART;      // NB
    int*      bbase   = btotal + NB;                      // NB+1

    const int chunk    = (E + KPART - 1) / KPART;         // 3125
    const int ngroups  = N * 16;
    const int cb       = (ngroups + 255) / 256;
    const int g_blocks = (int)(((long long)N * 32 + 255) / 256);
    const int d_blocks = (N + 31) / 32;

    // --- W powers ---
    wpow_kernel<<<8, THREADS, 0, stream>>>(W, w3t_hi, w3t_lo, nw2t_hi, nw2t_lo);

    // --- CSR build: LDS-binned two-pass partition (+ fused X->bf16) ---
    part_count_conv_kernel<<<cb + KPART, THREADS, 0, stream>>>(erows, E, blkcnt, NB,
                                                               chunk, X, xbf, ngroups, cb);
    part_scan1_kernel<<<(NB + 3) / 4, THREADS, 0, stream>>>(blkcnt, btotal, NB);
    part_scan2_kernel<<<1, 1024, 0, stream>>>(btotal, bbase, NB, E, rowptr, N);
    part_place_kernel<<<KPART, THREADS, 0, stream>>>(erows, ecols, evals, E, blkcnt,
                                                     bbase, NB, chunk, bucketed);
    part_finish_kernel<<<NB, THREADS, 0, stream>>>(bucketed, bbase, rowptr, csr, N);

    // --- Chebyshev chain (reassociated) ---
    // t2bf = bf16(2A.Xbf - X)
    spmm_gather_bf<true><<<g_blocks, THREADS, 0, stream>>>(rowptr, csr, xbf, X, t2bf, N);
    // u2 = 2A.t2bf  (f32; overwrites the dead bucketed alias)
    spmm_gather_bf<false><<<g_blocks, THREADS, 0, stream>>>(rowptr, csr, t2bf, nullptr, u2, N);
    // out = u2@W3 - X@W2
    gemm_dual_mfma<<<d_blocks, THREADS, 0, stream>>>(u2, w3t_hi, w3t_lo,
                                                     X, nw2t_hi, nw2t_lo, out, N);
}